// Round 1
// baseline (117.956 us; speedup 1.0000x reference)
//
#include <hip/hip_runtime.h>

typedef short bf16x8 __attribute__((ext_vector_type(8)));
typedef float f32x4 __attribute__((ext_vector_type(4)));

#define KDIM 256
#define BT 128
#define BK 64

__device__ __forceinline__ unsigned short f2bf(float f) {
  unsigned u = __float_as_uint(f);
  unsigned r = (u + 0x7fffu + ((u >> 16) & 1u)) >> 16;  // RNE
  return (unsigned short)r;
}
__device__ __forceinline__ float bf2f(unsigned short b) {
  return __uint_as_float(((unsigned)b) << 16);
}

__device__ __forceinline__ void async_cp16(const void* g, void* l) {
  __builtin_amdgcn_global_load_lds(
      (const __attribute__((address_space(1))) unsigned int*)g,
      (__attribute__((address_space(3))) unsigned int*)l, 16, 0, 0);
}

// Kernel 1: fp32 -> bf16 convert, row sq (of bf16-rounded vals), column sums, sum(sq).
__global__ __launch_bounds__(256) void mmd_stage(
    const float* __restrict__ src, const float* __restrict__ tgt, int ns,
    unsigned short* __restrict__ Tbf, float* __restrict__ sq,
    float* __restrict__ scol, float* __restrict__ sum_sq) {
  __shared__ float sp[256];
  __shared__ float rw[4];
  int t = threadIdx.x;
  int lane = t & 63, wave = t >> 6;
  sp[t] = 0.f;
  __syncthreads();
  int sub = t & 31;   // 8-elem group within row
  int rsel = t >> 5;  // row within 8-row group
  float colacc[8];
#pragma unroll
  for (int j = 0; j < 8; ++j) colacc[j] = 0.f;
  float tsq = 0.f;
  for (int it = 0; it < 16; ++it) {
    int r = blockIdx.x * 128 + it * 8 + rsel;
    const float* rp = (r < ns) ? (src + (size_t)r * KDIM)
                               : (tgt + (size_t)(r - ns) * KDIM);
    float4 v0 = *(const float4*)(rp + sub * 8);
    float4 v1 = *(const float4*)(rp + sub * 8 + 4);
    float vals[8] = {v0.x, v0.y, v0.z, v0.w, v1.x, v1.y, v1.z, v1.w};
    unsigned pk[4];
    float ssp = 0.f;
#pragma unroll
    for (int j = 0; j < 4; ++j) {
      unsigned short b0 = f2bf(vals[2 * j]);
      unsigned short b1 = f2bf(vals[2 * j + 1]);
      float x0 = bf2f(b0), x1 = bf2f(b1);
      pk[j] = (unsigned)b0 | ((unsigned)b1 << 16);
      ssp += x0 * x0 + x1 * x1;
      colacc[2 * j] += x0;
      colacc[2 * j + 1] += x1;
    }
    *(uint4*)(Tbf + (size_t)r * KDIM + sub * 8) =
        make_uint4(pk[0], pk[1], pk[2], pk[3]);
    tsq += ssp;
    float ss = ssp;
#pragma unroll
    for (int off = 16; off; off >>= 1) ss += __shfl_down(ss, off, 32);
    if (sub == 0) sq[r] = ss;
  }
#pragma unroll
  for (int j = 0; j < 8; ++j) atomicAdd(&sp[sub * 8 + j], colacc[j]);
#pragma unroll
  for (int off = 32; off; off >>= 1) tsq += __shfl_down(tsq, off, 64);
  if (lane == 0) rw[wave] = tsq;
  __syncthreads();
  atomicAdd(&scol[t], sp[t]);
  if (t == 0) atomicAdd(sum_sq, rw[0] + rw[1] + rw[2] + rw[3]);
}

// Kernel 2: bandwidth via sum(L2) = 2n*sum(sq) - 2*||colsum||^2; coef + zero accum.
__global__ void mmd_prep2(const float* __restrict__ scol,
                          const float* __restrict__ sum_sq,
                          float* __restrict__ coef, float* __restrict__ accum,
                          int n) {
  int t = threadIdx.x;
  float4 v = *(const float4*)(scol + t * 4);
  float p = v.x * v.x + v.y * v.y + v.z * v.z + v.w * v.w;
#pragma unroll
  for (int off = 32; off; off >>= 1) p += __shfl_down(p, off, 64);
  if (t == 0) {
    double ssq = (double)p;
    double S = (double)sum_sq[0];
    double nn = (double)n;
    double sumL2 = 2.0 * nn * S - 2.0 * ssq;
    double bw = sumL2 / (nn * nn - nn) / 4.0;  // /= KERNEL_MUL**(KERNEL_NUM//2)
#pragma unroll
    for (int i = 0; i < 5; ++i) coef[i] = (float)(-1.0 / (bw * (double)(1 << i)));
    accum[0] = 0.f;
  }
}

// Kernel 3: fused Gram-tile (MFMA) + L2 + 5-kernel sum + reduction.
// Lower-triangular 128x128 tiles; off-diagonal tiles weighted x2 (symmetry).
__global__ __launch_bounds__(256) void mmd_main(
    const unsigned short* __restrict__ Tbf, const float* __restrict__ sq,
    const float* __restrict__ coef, float* __restrict__ accum, int halfTiles) {
  __shared__ short As[BT * BK];
  __shared__ short Bs[BT * BK];
  __shared__ float sqa[BT];
  __shared__ float sqb[BT];
  __shared__ float red[4];

  int id = blockIdx.x;
  int bi = (int)((sqrtf(8.f * (float)id + 1.f) - 1.f) * 0.5f);
  while ((bi + 1) * (bi + 2) / 2 <= id) ++bi;
  while (bi * (bi + 1) / 2 > id) --bi;
  int bj = id - bi * (bi + 1) / 2;
  int rowBase = bi * BT, colBase = bj * BT;

  int t = threadIdx.x;
  int lane = t & 63, wave = t >> 6;

  if (t < 128) sqa[t] = sq[rowBase + t];
  else sqb[t - 128] = sq[colBase + (t - 128)];

  f32x4 acc[4][4];
#pragma unroll
  for (int a = 0; a < 4; ++a)
#pragma unroll
    for (int b = 0; b < 4; ++b) {
      f32x4 z = {0.f, 0.f, 0.f, 0.f};
      acc[a][b] = z;
    }

  int wrow = (wave >> 1) * 64, wcol = (wave & 1) * 64;
  // staging: lane -> (row=lane/8, swizzled kgroup = (lane%8) ^ (lane/8))
  int lrow = lane >> 3;
  int kgsw = (lane & 7) ^ lrow;
  // ds_read: fragment row = lane&15, k-quad = lane>>4
  int frow = lane & 15;
  int kq = lane >> 4;

  for (int c = 0; c < 4; ++c) {
    int k0 = c * BK;
#pragma unroll
    for (int j = 0; j < 4; ++j) {
      int R0 = j * 32 + wave * 8;
      int ldsoff = (j * 256 + wave * 64) * 8;  // shorts; HW adds lane*16B
      async_cp16(Tbf + (size_t)(rowBase + R0 + lrow) * KDIM + k0 + kgsw * 8,
                 &As[ldsoff]);
      async_cp16(Tbf + (size_t)(colBase + R0 + lrow) * KDIM + k0 + kgsw * 8,
                 &Bs[ldsoff]);
    }
    __syncthreads();
#pragma unroll
    for (int ks = 0; ks < 2; ++ks) {
      bf16x8 af[4], bfv[4];
#pragma unroll
      for (int mt = 0; mt < 4; ++mt) {
        int r = wrow + mt * 16 + frow;
        int pg = (ks * 4 + kq) ^ (r & 7);  // undo XOR swizzle
        af[mt] = *(const bf16x8*)&As[r * BK + pg * 8];
      }
#pragma unroll
      for (int nt = 0; nt < 4; ++nt) {
        int r = wcol + nt * 16 + frow;
        int pg = (ks * 4 + kq) ^ (r & 7);
        bfv[nt] = *(const bf16x8*)&Bs[r * BK + pg * 8];
      }
#pragma unroll
      for (int mt = 0; mt < 4; ++mt)
#pragma unroll
        for (int nt = 0; nt < 4; ++nt)
          acc[mt][nt] = __builtin_amdgcn_mfma_f32_16x16x32_bf16(
              af[mt], bfv[nt], acc[mt][nt], 0, 0, 0);
    }
    __syncthreads();
  }

  // epilogue: C/D layout col=lane&15, row=(lane>>4)*4+reg  [m89]
  float c4 = coef[4];  // -1/(16*bw); e_{i-1} = e_i^2
  float lsum = 0.f;
  int ccol = lane & 15;
  int rb = (lane >> 4) * 4;
#pragma unroll
  for (int mt = 0; mt < 4; ++mt) {
#pragma unroll
    for (int nt = 0; nt < 4; ++nt) {
      float sb = sqb[wcol + nt * 16 + ccol];
#pragma unroll
      for (int rg = 0; rg < 4; ++rg) {
        float g = acc[mt][nt][rg];
        float l2 = sqa[wrow + mt * 16 + rb + rg] + sb - 2.f * g;
        float e = __expf(l2 * c4);
        float v = e;
        e = e * e; v += e;
        e = e * e; v += e;
        e = e * e; v += e;
        e = e * e; v += e;
        lsum += v;
      }
    }
  }
#pragma unroll
  for (int off = 32; off; off >>= 1) lsum += __shfl_down(lsum, off, 64);
  if (lane == 0) red[wave] = lsum;
  __syncthreads();
  if (t == 0) {
    float w = ((bi < halfTiles) == (bj < halfTiles)) ? 1.f : -1.f;
    float f = (bi == bj) ? 1.f : 2.f;
    atomicAdd(accum, w * f * (red[0] + red[1] + red[2] + red[3]));
  }
}

__global__ void mmd_fin(const float* __restrict__ accum, float* __restrict__ out,
                        float inv) {
  out[0] = accum[0] * inv;
}

extern "C" void kernel_launch(void* const* d_in, const int* in_sizes, int n_in,
                              void* d_out, int out_size, void* d_ws,
                              size_t ws_size, hipStream_t stream) {
  const float* src = (const float*)d_in[0];
  const float* tgt = (const float*)d_in[1];
  int ns = in_sizes[0] / KDIM;   // 4096
  int ntr = in_sizes[1] / KDIM;  // 4096
  int n = ns + ntr;              // 8192

  char* ws = (char*)d_ws;
  unsigned short* Tbf = (unsigned short*)ws;  // 4 MiB bf16 matrix
  size_t off = (size_t)n * KDIM * sizeof(unsigned short);
  float* sq = (float*)(ws + off);     off += (size_t)n * 4;
  float* scol = (float*)(ws + off);   off += (size_t)KDIM * 4;
  float* sum_sq = (float*)(ws + off); off += 4;
  float* accum = (float*)(ws + off);  off += 4;
  float* coef = (float*)(ws + off);

  // zero scol + sum_sq + accum (ws is poisoned 0xAA before every call)
  hipMemsetAsync(scol, 0, (KDIM + 2) * sizeof(float), stream);

  mmd_stage<<<n / 128, 256, 0, stream>>>(src, tgt, ns, Tbf, sq, scol, sum_sq);
  mmd_prep2<<<1, 64, 0, stream>>>(scol, sum_sq, coef, accum, n);
  int nb = n / BT;               // 64
  int nblk = nb * (nb + 1) / 2;  // 2080
  mmd_main<<<nblk, 256, 0, stream>>>(Tbf, sq, coef, accum, ns / BT);
  mmd_fin<<<1, 1, 0, stream>>>(accum, (float*)d_out,
                               1.f / ((float)ns * (float)ns));
}

// Round 2
// 110.886 us; speedup vs baseline: 1.0638x; 1.0638x over previous
//
#include <hip/hip_runtime.h>

typedef short bf16x8 __attribute__((ext_vector_type(8)));
typedef float f32x4 __attribute__((ext_vector_type(4)));

#define KDIM 256
#define BT 128
#define BK 64

__device__ __forceinline__ unsigned short f2bf(float f) {
  unsigned u = __float_as_uint(f);
  unsigned r = (u + 0x7fffu + ((u >> 16) & 1u)) >> 16;  // RNE
  return (unsigned short)r;
}
__device__ __forceinline__ float bf2f(unsigned short b) {
  return __uint_as_float(((unsigned)b) << 16);
}

__device__ __forceinline__ void async_cp16(const void* g, void* l) {
  __builtin_amdgcn_global_load_lds(
      (const __attribute__((address_space(1))) unsigned int*)g,
      (__attribute__((address_space(3))) unsigned int*)l, 16, 0, 0);
}

// Kernel 1: fp32 -> bf16 convert, row sq (of bf16-rounded vals), column sums,
// sum(sq). 256 blocks x 32 rows (was 64 blocks — latency-bound).
__global__ __launch_bounds__(256) void mmd_stage(
    const float* __restrict__ src, const float* __restrict__ tgt, int ns,
    unsigned short* __restrict__ Tbf, float* __restrict__ sq,
    float* __restrict__ scol, float* __restrict__ sum_sq) {
  __shared__ float sp[256];
  __shared__ float rw[4];
  int t = threadIdx.x;
  int lane = t & 63, wave = t >> 6;
  sp[t] = 0.f;
  __syncthreads();
  int sub = t & 31;   // 8-elem group within row
  int rsel = t >> 5;  // row within 8-row group
  float colacc[8];
#pragma unroll
  for (int j = 0; j < 8; ++j) colacc[j] = 0.f;
  float tsq = 0.f;
#pragma unroll
  for (int it = 0; it < 4; ++it) {
    int r = blockIdx.x * 32 + it * 8 + rsel;
    const float* rp = (r < ns) ? (src + (size_t)r * KDIM)
                               : (tgt + (size_t)(r - ns) * KDIM);
    float4 v0 = *(const float4*)(rp + sub * 8);
    float4 v1 = *(const float4*)(rp + sub * 8 + 4);
    float vals[8] = {v0.x, v0.y, v0.z, v0.w, v1.x, v1.y, v1.z, v1.w};
    unsigned pk[4];
    float ssp = 0.f;
#pragma unroll
    for (int j = 0; j < 4; ++j) {
      unsigned short b0 = f2bf(vals[2 * j]);
      unsigned short b1 = f2bf(vals[2 * j + 1]);
      float x0 = bf2f(b0), x1 = bf2f(b1);
      pk[j] = (unsigned)b0 | ((unsigned)b1 << 16);
      ssp += x0 * x0 + x1 * x1;
      colacc[2 * j] += x0;
      colacc[2 * j + 1] += x1;
    }
    *(uint4*)(Tbf + (size_t)r * KDIM + sub * 8) =
        make_uint4(pk[0], pk[1], pk[2], pk[3]);
    tsq += ssp;
    float ss = ssp;
#pragma unroll
    for (int off = 16; off; off >>= 1) ss += __shfl_down(ss, off, 32);
    if (sub == 0) sq[r] = ss;
  }
#pragma unroll
  for (int j = 0; j < 8; ++j) atomicAdd(&sp[sub * 8 + j], colacc[j]);
#pragma unroll
  for (int off = 32; off; off >>= 1) tsq += __shfl_down(tsq, off, 64);
  if (lane == 0) rw[wave] = tsq;
  __syncthreads();
  atomicAdd(&scol[t], sp[t]);
  if (t == 0) atomicAdd(sum_sq, rw[0] + rw[1] + rw[2] + rw[3]);
}

// Kernel 2: bandwidth via sum(L2) = 2n*sum(sq) - 2*||colsum||^2.
// Stores coef pre-multiplied by log2(e) (main uses exp2), zeroes d_out.
__global__ void mmd_prep2(const float* __restrict__ scol,
                          const float* __restrict__ sum_sq,
                          float* __restrict__ coef, float* __restrict__ out,
                          int n) {
  int t = threadIdx.x;
  float4 v = *(const float4*)(scol + t * 4);
  float p = v.x * v.x + v.y * v.y + v.z * v.z + v.w * v.w;
#pragma unroll
  for (int off = 32; off; off >>= 1) p += __shfl_down(p, off, 64);
  if (t == 0) {
    double ssq = (double)p;
    double S = (double)sum_sq[0];
    double nn = (double)n;
    double sumL2 = 2.0 * nn * S - 2.0 * ssq;
    double bw = sumL2 / (nn * nn - nn) / 4.0;  // /= KERNEL_MUL**(KERNEL_NUM//2)
    double l2e = 1.4426950408889634;
#pragma unroll
    for (int i = 0; i < 5; ++i)
      coef[i] = (float)(-l2e / (bw * (double)(1 << i)));
    out[0] = 0.f;
  }
}

__device__ __forceinline__ float2 pk_add(float2 a, float2 b) {
  return make_float2(a.x + b.x, a.y + b.y);
}
__device__ __forceinline__ float2 pk_mul(float2 a, float2 b) {
  return make_float2(a.x * b.x, a.y * b.y);
}
__device__ __forceinline__ float2 pk_fma(float2 a, float2 b, float2 c) {
  return make_float2(__builtin_fmaf(a.x, b.x, c.x),
                     __builtin_fmaf(a.y, b.y, c.y));
}

// Kernel 3: fused Gram-tile (MFMA) + L2 + 5-kernel sum + reduction.
// Lower-triangular 128x128 tiles; off-diagonal tiles weighted x2 (symmetry).
// Scaled atomicAdd straight into d_out (zeroed by prep2).
__global__ __launch_bounds__(256) void mmd_main(
    const unsigned short* __restrict__ Tbf, const float* __restrict__ sq,
    const float* __restrict__ coef, float* __restrict__ out, int halfTiles,
    float inv) {
  __shared__ short As[BT * BK];
  __shared__ short Bs[BT * BK];
  __shared__ float sqa[BT];
  __shared__ float sqb[BT];
  __shared__ float red[4];

  int id = blockIdx.x;
  int bi = (int)((sqrtf(8.f * (float)id + 1.f) - 1.f) * 0.5f);
  while ((bi + 1) * (bi + 2) / 2 <= id) ++bi;
  while (bi * (bi + 1) / 2 > id) --bi;
  int bj = id - bi * (bi + 1) / 2;
  int rowBase = bi * BT, colBase = bj * BT;

  int t = threadIdx.x;
  int lane = t & 63, wave = t >> 6;

  if (t < 128) sqa[t] = sq[rowBase + t];
  else sqb[t - 128] = sq[colBase + (t - 128)];

  f32x4 acc[4][4];
#pragma unroll
  for (int a = 0; a < 4; ++a)
#pragma unroll
    for (int b = 0; b < 4; ++b) {
      f32x4 z = {0.f, 0.f, 0.f, 0.f};
      acc[a][b] = z;
    }

  int wrow = (wave >> 1) * 64, wcol = (wave & 1) * 64;
  // staging: lane -> (row=lane/8, swizzled kgroup = (lane%8) ^ (lane/8))
  int lrow = lane >> 3;
  int kgsw = (lane & 7) ^ lrow;
  // ds_read: fragment row = lane&15, k-quad = lane>>4
  int frow = lane & 15;
  int kq = lane >> 4;

  for (int c = 0; c < 4; ++c) {
    int k0 = c * BK;
#pragma unroll
    for (int j = 0; j < 4; ++j) {
      int R0 = j * 32 + wave * 8;
      int ldsoff = (j * 256 + wave * 64) * 8;  // shorts; HW adds lane*16B
      async_cp16(Tbf + (size_t)(rowBase + R0 + lrow) * KDIM + k0 + kgsw * 8,
                 &As[ldsoff]);
      async_cp16(Tbf + (size_t)(colBase + R0 + lrow) * KDIM + k0 + kgsw * 8,
                 &Bs[ldsoff]);
    }
    __syncthreads();
#pragma unroll
    for (int ks = 0; ks < 2; ++ks) {
      bf16x8 af[4], bfv[4];
#pragma unroll
      for (int mt = 0; mt < 4; ++mt) {
        int r = wrow + mt * 16 + frow;
        int pg = (ks * 4 + kq) ^ (r & 7);  // undo XOR swizzle
        af[mt] = *(const bf16x8*)&As[r * BK + pg * 8];
      }
#pragma unroll
      for (int nt = 0; nt < 4; ++nt) {
        int r = wcol + nt * 16 + frow;
        int pg = (ks * 4 + kq) ^ (r & 7);
        bfv[nt] = *(const bf16x8*)&Bs[r * BK + pg * 8];
      }
#pragma unroll
      for (int mt = 0; mt < 4; ++mt)
#pragma unroll
        for (int nt = 0; nt < 4; ++nt)
          acc[mt][nt] = __builtin_amdgcn_mfma_f32_16x16x32_bf16(
              af[mt], bfv[nt], acc[mt][nt], 0, 0, 0);
    }
    __syncthreads();
  }

  // epilogue: C/D layout col=lane&15, row=(lane>>4)*4+reg  [m89]
  // e = exp2(c4*L2) with c4 = -log2e/(16bw); kernels sum = e+e^2+e^4+e^8+e^16.
  // float2-packed to hit v_pk_* dual-issue f32 ops.
  float c4 = coef[4];
  float m2c4 = -2.f * c4;
  float2 m2v = make_float2(m2c4, m2c4);
  int ccol = lane & 15;
  int rb = (lane >> 4) * 4;
  float ra[16];
#pragma unroll
  for (int mt = 0; mt < 4; ++mt)
#pragma unroll
    for (int rg = 0; rg < 4; ++rg)
      ra[mt * 4 + rg] = sqa[wrow + mt * 16 + rb + rg] * c4;
  float cbv[4];
#pragma unroll
  for (int nt = 0; nt < 4; ++nt) cbv[nt] = sqb[wcol + nt * 16 + ccol] * c4;

  float2 lsum2 = make_float2(0.f, 0.f);
#pragma unroll
  for (int mt = 0; mt < 4; ++mt) {
#pragma unroll
    for (int nt = 0; nt < 4; ++nt) {
      float cb = cbv[nt];
#pragma unroll
      for (int rp = 0; rp < 4; rp += 2) {
        float2 g = make_float2(acc[mt][nt][rp], acc[mt][nt][rp + 1]);
        float2 sab = make_float2(ra[mt * 4 + rp] + cb, ra[mt * 4 + rp + 1] + cb);
        float2 u = pk_fma(g, m2v, sab);
        float2 e = make_float2(__builtin_amdgcn_exp2f(u.x),
                               __builtin_amdgcn_exp2f(u.y));
        float2 e2 = pk_mul(e, e);
        float2 e4 = pk_mul(e2, e2);
        float2 e8 = pk_mul(e4, e4);
        float2 s = pk_add(e, e2);
        s = pk_add(s, e4);
        s = pk_add(s, e8);
        s = pk_fma(e8, e8, s);  // + e^16
        lsum2 = pk_add(lsum2, s);
      }
    }
  }
  float lsum = lsum2.x + lsum2.y;
#pragma unroll
  for (int off = 32; off; off >>= 1) lsum += __shfl_down(lsum, off, 64);
  if (lane == 0) red[wave] = lsum;
  __syncthreads();
  if (t == 0) {
    float w = ((bi < halfTiles) == (bj < halfTiles)) ? 1.f : -1.f;
    float f = (bi == bj) ? 1.f : 2.f;
    atomicAdd(out, w * f * inv * (red[0] + red[1] + red[2] + red[3]));
  }
}

extern "C" void kernel_launch(void* const* d_in, const int* in_sizes, int n_in,
                              void* d_out, int out_size, void* d_ws,
                              size_t ws_size, hipStream_t stream) {
  const float* src = (const float*)d_in[0];
  const float* tgt = (const float*)d_in[1];
  int ns = in_sizes[0] / KDIM;   // 4096
  int ntr = in_sizes[1] / KDIM;  // 4096
  int n = ns + ntr;              // 8192

  char* ws = (char*)d_ws;
  unsigned short* Tbf = (unsigned short*)ws;  // 4 MiB bf16 matrix
  size_t off = (size_t)n * KDIM * sizeof(unsigned short);
  float* sq = (float*)(ws + off);     off += (size_t)n * 4;
  float* scol = (float*)(ws + off);   off += (size_t)KDIM * 4;
  float* sum_sq = (float*)(ws + off); off += 4;
  float* coef = (float*)(ws + off);

  // zero scol + sum_sq (ws is poisoned 0xAA before every call)
  hipMemsetAsync(scol, 0, (KDIM + 1) * sizeof(float), stream);

  mmd_stage<<<n / 32, 256, 0, stream>>>(src, tgt, ns, Tbf, sq, scol, sum_sq);
  mmd_prep2<<<1, 64, 0, stream>>>(scol, sum_sq, coef, (float*)d_out, n);
  int nb = n / BT;               // 64
  int nblk = nb * (nb + 1) / 2;  // 2080
  mmd_main<<<nblk, 256, 0, stream>>>(Tbf, sq, coef, (float*)d_out, ns / BT,
                                     1.f / ((float)ns * (float)ns));
}